// Round 6
// baseline (85.120 us; speedup 1.0000x reference)
//
#include <hip/hip_runtime.h>

// PixelShift: out[c,d,i,j] = x[c,d,(i - s0[d]) & 1023, (j - s1[d]) & 1023]
// C=4, D=16, H=W=1024, float32. Memory-bound circular roll per depth slice.
//
// R5 -> R6: explicit 4-wide batch. Issue all A-loads + masked lane-63 patch
// loads before any use (one wait covers all), then shfl/select/store tails.
// Breaks the load->shfl->patch-load serial chain; 4x the bytes in flight.

#define CC 4
#define DD 16
#define HH 1024
#define WW 1024

typedef float floatx4 __attribute__((ext_vector_type(4)));

__global__ __launch_bounds__(256)
void PixelShift_kernel(const float* __restrict__ x,
                       const int* __restrict__ shift,
                       float* __restrict__ out) {
    __shared__ int s_sh[2 * DD];
    if (threadIdx.x < 2 * DD) s_sh[threadIdx.x] = shift[threadIdx.x];
    __syncthreads();

    const int lane   = threadIdx.x & 63;
    const int tid    = blockIdx.x * blockDim.x + threadIdx.x;
    const int stride = gridDim.x * blockDim.x;            // 524288
    constexpr int TOTAL4 = CC * DD * HH * (WW / 4);       // 16,777,216
    constexpr int BATCH  = 4;                              // 8 outer iters exact

    for (int t0 = tid; t0 < TOTAL4; t0 += stride * BATCH) {
        floatx4 A[BATCH], P[BATCH];
        int srem[BATCH], tA[BATCH];

        // Phase 1: issue ALL loads (A + masked patch) before any use.
#pragma unroll
        for (int k = 0; k < BATCH; ++k) {
            const int t  = t0 + k * stride;
            tA[k] = t;
            const int j4 = t & (WW / 4 - 1);
            const int r  = t >> 8;
            const int i  = r & (HH - 1);
            const int cd = r >> 10;
            const int d  = cd & (DD - 1);

            const int s0 = s_sh[2 * d];
            const int s1 = s_sh[2 * d + 1];

            const int si = (i - s0) & (HH - 1);
            const floatx4* __restrict__ row4 =
                reinterpret_cast<const floatx4*>(x + ((size_t)cd * HH + si) * WW);

            const int js = ((j4 << 2) - s1) & (WW - 1);
            const int a0 = js >> 2;
            srem[k] = js & 3;

            A[k] = row4[a0];                              // aligned 16B load
            if (lane == 63 && srem[k] != 0)               // patch: independent addr,
                P[k] = row4[(a0 + 1) & (WW / 4 - 1)];     // issues with A-loads
        }

        // Phase 2: realign in-register and store.
#pragma unroll
        for (int k = 0; k < BATCH; ++k) {
            const floatx4 Ak = A[k];
            floatx4 v;
            if (srem[k] == 0) {                           // wave-uniform branch
                v = Ak;
            } else {
                floatx4 B;
                B.x = __shfl_down(Ak.x, 1);
                B.y = __shfl_down(Ak.y, 1);
                B.z = __shfl_down(Ak.z, 1);
                B.w = __shfl_down(Ak.w, 1);
                if (lane == 63) B = P[k];
                if (srem[k] == 1)      v = (floatx4){Ak.y, Ak.z, Ak.w, B.x};
                else if (srem[k] == 2) v = (floatx4){Ak.z, Ak.w, B.x, B.y};
                else                   v = (floatx4){Ak.w, B.x, B.y, B.z};
            }
            // NT store: streaming output must not evict x from L2/L3.
            __builtin_nontemporal_store(v, reinterpret_cast<floatx4*>(out) + tA[k]);
        }
    }
}

extern "C" void kernel_launch(void* const* d_in, const int* in_sizes, int n_in,
                              void* d_out, int out_size, void* d_ws, size_t ws_size,
                              hipStream_t stream) {
    const float* x     = (const float*)d_in[0];
    const int*   shift = (const int*)d_in[1];
    float*       out   = (float*)d_out;

    const int blocks  = 2048;  // 2048*256 threads -> 32 chunks/thread, 8 batched iters
    const int threads = 256;
    PixelShift_kernel<<<blocks, threads, 0, stream>>>(x, shift, out);
}

// Round 7
// 81.056 us; speedup vs baseline: 1.0501x; 1.0501x over previous
//
#include <hip/hip_runtime.h>

// PixelShift: out[c,d,i,j] = x[c,d,(i - s0[d]) & 1023, (j - s1[d]) & 1023]
// C=4, D=16, H=W=1024, float32. Memory-bound circular roll per depth slice.
//
// R6 -> R7: revert to R5 structure (batching regressed). Store now uses
// inline-asm global_store_dwordx4 with sc0 sc1 nt (system-scope,
// no-allocate): __builtin_nontemporal_store's nt bit alone leaves the
// 268 MB write stream allocating in the Infinity Cache, evicting ~half of
// the 256 MiB input per pass (steady-state FETCH == 134 MB matches).
// Full bypass should keep x L3-resident -> read misses ~0.

#define CC 4
#define DD 16
#define HH 1024
#define WW 1024

typedef float floatx4 __attribute__((ext_vector_type(4)));

__global__ __launch_bounds__(256)
void PixelShift_kernel(const float* __restrict__ x,
                       const int* __restrict__ shift,
                       float* __restrict__ out) {
    __shared__ int s_sh[2 * DD];
    if (threadIdx.x < 2 * DD) s_sh[threadIdx.x] = shift[threadIdx.x];
    __syncthreads();

    const int lane   = threadIdx.x & 63;
    const int total4 = CC * DD * HH * (WW / 4);           // 16,777,216 float4s
    const int stride = gridDim.x * blockDim.x;
#pragma unroll 2
    for (int t = blockIdx.x * blockDim.x + threadIdx.x; t < total4; t += stride) {
        const int j4 = t & (WW / 4 - 1);                  // 0..255
        const int r  = t >> 8;                            // cd*H + i
        const int i  = r & (HH - 1);
        const int cd = r >> 10;                           // c*D + d
        const int d  = cd & (DD - 1);

        const int s0 = s_sh[2 * d];
        const int s1 = s_sh[2 * d + 1];

        const int si = (i - s0) & (HH - 1);
        const floatx4* __restrict__ row4 =
            reinterpret_cast<const floatx4*>(x + ((size_t)cd * HH + si) * WW);

        const int js   = ((j4 << 2) - s1) & (WW - 1);     // source float offset
        const int a0   = js >> 2;                         // aligned float4 index
        const int srem = js & 3;                          // wave-uniform (= (-s1)&3)

        const floatx4 A = row4[a0];                       // 16B-aligned load
        floatx4 v;
        if (srem == 0) {
            v = A;
        } else {
            // Neighbor lane's A (lane l+1 holds source float4 a0+1).
            floatx4 B;
            B.x = __shfl_down(A.x, 1);
            B.y = __shfl_down(A.y, 1);
            B.z = __shfl_down(A.z, 1);
            B.w = __shfl_down(A.w, 1);
            // Lane 63 has no in-wave neighbor: one aligned patch load
            // (wraps within the row; row base is 16B-aligned).
            if (lane == 63) B = row4[(a0 + 1) & (WW / 4 - 1)];

            if (srem == 1)      v = (floatx4){A.y, A.z, A.w, B.x};
            else if (srem == 2) v = (floatx4){A.z, A.w, B.x, B.y};
            else                v = (floatx4){A.w, B.x, B.y, B.z};
        }

        // System-scope no-allocate streaming store: bypass L2 AND the
        // Infinity Cache so the output stream never evicts x.
        floatx4* dst = reinterpret_cast<floatx4*>(out) + t;
        asm volatile("global_store_dwordx4 %0, %1, off sc0 sc1 nt"
                     :: "v"(dst), "v"(v) : "memory");
    }
}

extern "C" void kernel_launch(void* const* d_in, const int* in_sizes, int n_in,
                              void* d_out, int out_size, void* d_ws, size_t ws_size,
                              hipStream_t stream) {
    const float* x     = (const float*)d_in[0];
    const int*   shift = (const int*)d_in[1];
    float*       out   = (float*)d_out;

    const int blocks  = 2048;  // 256 CUs x 8 blocks, grid-stride covers the rest
    const int threads = 256;
    PixelShift_kernel<<<blocks, threads, 0, stream>>>(x, shift, out);
}